// Round 1
// baseline (812.239 us; speedup 1.0000x reference)
//
#include <hip/hip_runtime.h>

typedef _Float16 half8 __attribute__((ext_vector_type(8)));
typedef float    f32x4 __attribute__((ext_vector_type(4)));

#define NB  256
#define NH  512
#define NSQ 256
#define NSP 256

// One workgroup = (batch b, q-tile of 64 rows). 256 threads = 4 waves.
// Phase 1: S(64x256) = Q^T P via mfma_f32_16x16x32_f16, S lives in accumulators.
// Softmax in registers (C-layout row-wise reduce via shfl_xor over lanes 0..15).
// Phase 2: q~ = att @ P^T, P staged naturally (p = k is contiguous), epilogue
// writes 4 segments with 64B-contiguous-per-row float4 stores.
__global__ __launch_bounds__(256, 2)
void rmatch_kernel(const float* __restrict__ Q, const float* __restrict__ P,
                   const int* __restrict__ QM, const int* __restrict__ PM,
                   float* __restrict__ out)
{
    // LDS: union(p1 staging 25.0K, p2 staging 16.5K) + att 33.0K + qtl 9.0K = 68.6 KiB -> 2 WG/CU
    __shared__ union {
        struct { _Float16 A[64][40];  _Float16 Bm[256][40]; } p1; // [m|n][k], stride 40 halfs (80B, 16B-aligned)
        struct { _Float16 P2[32][264]; } p2;                      // [h][p], stride 264 halfs (528B)
    } stg;
    __shared__ _Float16 att[64][264];  // [q][p] f16, A-operand layout for phase 2
    __shared__ float    qtl[64][36];   // [q][h-chunk] fp32 staging of q~, stride 36 f32 (144B)

    const int tid  = threadIdx.x;
    const int b    = blockIdx.x >> 2;
    const int q0   = (blockIdx.x & 3) << 6;
    const int w    = tid >> 6;      // wave id
    const int lane = tid & 63;
    const int c    = lane & 15;     // mfma "col" lane field
    const int g    = lane >> 4;     // mfma quad

    const float* Qg = Q + (size_t)b * NH * NSQ;   // [h][q], q contiguous
    const float* Pg = P + (size_t)b * NH * NSP;   // [h][p], p contiguous

    f32x4 acc1[16];
#pragma unroll
    for (int nt = 0; nt < 16; ++nt) { f32x4 z = {0.f,0.f,0.f,0.f}; acc1[nt] = z; }

    const int aL = tid & 63;   // A-staging row (q index)
    const int aB = tid >> 6;   // A-staging 8-half block

    // ---------------- phase 1: S = Q^T P, k-chunks of 32 h ----------------
    for (int kc = 0; kc < 16; ++kc) {
        const int h0 = kc * 32;
        // stage A: Q^T tile [q=64][h=32]; lane gathers 8 h (coalesced across q per load)
        {
            half8 hv;
#pragma unroll
            for (int j = 0; j < 8; ++j)
                hv[j] = (_Float16)Qg[(h0 + aB*8 + j) * NSQ + q0 + aL];
            *(half8*)&stg.p1.A[aL][aB*8] = hv;
        }
        // stage B: P^T tile [p=256][h=32]
#pragma unroll
        for (int it = 0; it < 4; ++it) {
            half8 hv;
#pragma unroll
            for (int j = 0; j < 8; ++j)
                hv[j] = (_Float16)Pg[(h0 + it*8 + j) * NSP + tid];
            *(half8*)&stg.p1.Bm[tid][it*8] = hv;
        }
        __syncthreads();
        half8 av = *(const half8*)&stg.p1.A[16*w + c][g*8];
#pragma unroll
        for (int nt = 0; nt < 16; ++nt) {
            half8 bv = *(const half8*)&stg.p1.Bm[nt*16 + c][g*8];
            acc1[nt] = __builtin_amdgcn_mfma_f32_16x16x32_f16(av, bv, acc1[nt], 0, 0, 0);
        }
        __syncthreads();
    }

    // ---------------- masked softmax over p, in registers ----------------
    // lane holds S[row = 16w + 4g + reg][p = nt*16 + c]
    {
        const int* qm = QM + b * NSQ + q0;
        const int* pm = PM + b * NSP;
        int pmv[16];
#pragma unroll
        for (int nt = 0; nt < 16; ++nt) pmv[nt] = pm[nt*16 + c];
#pragma unroll
        for (int reg = 0; reg < 4; ++reg) {
            const int row = 16*w + 4*g + reg;
            const int qmv = qm[row];
            float mx = -3.0e38f;
#pragma unroll
            for (int nt = 0; nt < 16; ++nt) {
                float v = acc1[nt][reg];
                if (qmv & pmv[nt]) v += -1000000.0f;   // NEG_INF mask
                acc1[nt][reg] = v;
                mx = fmaxf(mx, v);
            }
#pragma unroll
            for (int xm = 1; xm < 16; xm <<= 1)
                mx = fmaxf(mx, __shfl_xor(mx, xm, 64));
            float s = 0.f;
#pragma unroll
            for (int nt = 0; nt < 16; ++nt) {
                float e = __expf(acc1[nt][reg] - mx);
                acc1[nt][reg] = e;
                s += e;
            }
#pragma unroll
            for (int xm = 1; xm < 16; xm <<= 1)
                s += __shfl_xor(s, xm, 64);
            const float inv = 1.0f / s;
#pragma unroll
            for (int nt = 0; nt < 16; ++nt)
                att[row][nt*16 + c] = (_Float16)(acc1[nt][reg] * inv);
        }
    }
    __syncthreads();

    // ---------------- phase 2: q~ = att @ P^T, h-chunks of 32 ----------------
    for (int hc = 0; hc < 16; ++hc) {
        const int h1 = hc * 32;
        // stage P2 [h=32][p=256] f16, natural layout (k = p contiguous)
#pragma unroll
        for (int it = 0; it < 4; ++it) {
            const int tk  = tid + 256*it;       // 0..1023
            const int row = tk >> 5;            // 0..31
            const int c8  = tk & 31;            // 8-half block
            const float* src = &Pg[(h1 + row) * NSP + c8*8];
            f32x4 x0 = *(const f32x4*)src;
            f32x4 x1 = *(const f32x4*)(src + 4);
            half8 hv;
#pragma unroll
            for (int l = 0; l < 4; ++l) { hv[l] = (_Float16)x0[l]; hv[4+l] = (_Float16)x1[l]; }
            *(half8*)&stg.p2.P2[row][c8*8] = hv;
        }
        __syncthreads();

        f32x4 acc2[2];
        { f32x4 z = {0.f,0.f,0.f,0.f}; acc2[0] = z; acc2[1] = z; }
#pragma unroll
        for (int ks = 0; ks < 8; ++ks) {
            half8 av = *(const half8*)&att[16*w + c][ks*32 + g*8];
#pragma unroll
            for (int nt = 0; nt < 2; ++nt) {
                half8 bv = *(const half8*)&stg.p2.P2[nt*16 + c][ks*32 + g*8];
                acc2[nt] = __builtin_amdgcn_mfma_f32_16x16x32_f16(av, bv, acc2[nt], 0, 0, 0);
            }
        }
        // q~ C-layout -> LDS fp32
#pragma unroll
        for (int nt = 0; nt < 2; ++nt)
#pragma unroll
            for (int reg = 0; reg < 4; ++reg)
                qtl[16*w + 4*g + reg][nt*16 + c] = acc2[nt][reg];
        __syncthreads();

        // epilogue: 4 threads per q-row, float4 stores (4 lanes = 64B contiguous per row)
        {
            const int qq = tid >> 2, hg = tid & 3;
            float* ob = out + ((size_t)(b * NSQ + q0 + qq)) * 2048 + h1;
#pragma unroll
            for (int j = 0; j < 2; ++j) {
                const int h4 = hg + 4*j;               // 0..7 (float4 group within 32-h chunk)
                f32x4 t4 = *(const f32x4*)&qtl[qq][h4*4];
                f32x4 qt;
#pragma unroll
                for (int l = 0; l < 4; ++l)
                    qt[l] = Qg[(h1 + h4*4 + l) * NSQ + q0 + qq];  // 4 h-rows x 64B per load inst
                f32x4 df = qt - t4;
                f32x4 pr = qt * t4;
                *(f32x4*)&ob[        h4*4] = qt;
                *(f32x4*)&ob[ 512  + h4*4] = t4;
                *(f32x4*)&ob[1024  + h4*4] = df;
                *(f32x4*)&ob[1536  + h4*4] = pr;
            }
        }
        __syncthreads();
    }
}

extern "C" void kernel_launch(void* const* d_in, const int* in_sizes, int n_in,
                              void* d_out, int out_size, void* d_ws, size_t ws_size,
                              hipStream_t stream)
{
    const float* Q  = (const float*)d_in[0];
    const float* P  = (const float*)d_in[1];
    const int*   QM = (const int*)d_in[2];
    const int*   PM = (const int*)d_in[3];
    float* o = (float*)d_out;
    rmatch_kernel<<<dim3(NB * 4), dim3(256), 0, stream>>>(Q, P, QM, PM, o);
}